// Round 23
// baseline (292.184 us; speedup 1.0000x reference)
//
#include <hip/hip_runtime.h>

#define BATCH 16
#define NQ 2048
#define NK 2048

typedef short s16x8 __attribute__((ext_vector_type(8)));
typedef __bf16 bf16x8 __attribute__((ext_vector_type(8)));
typedef float f32x16 __attribute__((ext_vector_type(16)));
typedef float f32x4 __attribute__((ext_vector_type(4)));
typedef int i32x4 __attribute__((ext_vector_type(4)));

static __device__ __forceinline__ unsigned short f2bf(float f) {
  unsigned u = __builtin_bit_cast(unsigned, f);
  u += 0x7FFFu + ((u >> 16) & 1u);   // round-to-nearest-even
  return (unsigned short)(u >> 16);
}

static __device__ __forceinline__ f32x16 mfma32(s16x8 a, s16x8 b, f32x16 c) {
  return __builtin_amdgcn_mfma_f32_32x32x16_bf16(
      __builtin_bit_cast(bf16x8, a), __builtin_bit_cast(bf16x8, b), c, 0, 0, 0);
}

static __device__ __forceinline__ f32x4 mfma16(s16x8 a, s16x8 b, f32x4 c) {
  return __builtin_amdgcn_mfma_f32_16x16x32_bf16(
      __builtin_bit_cast(bf16x8, a), __builtin_bit_cast(bf16x8, b), c, 0, 0, 0);
}

// p = exp(10*tanh(s) - 10) = exp2(-28.8539.../(e^(2s)+1)), e^(2s)=exp2(2.88539*s)
static __device__ __forceinline__ float score_p(float s) {
  float u = __builtin_amdgcn_exp2f(s * 2.885390081777927f);
  return __builtin_amdgcn_exp2f(-28.853900817779268f * __builtin_amdgcn_rcpf(u + 1.0f));
}

// MERGED prep kernel (R22, at HBM roofline ~56 us): pack_adj + projections.
//  - blocks 0..255:   K projection (blocks stage their own W^T in LDS)
//  - blocks 256..511: Q projection (scale 1/16 folded)
//  - blocks 512..8703: adjacency bit-pack (NT i32x4 + nibble/shfl-OR)
__global__ __launch_bounds__(256, 2) void prep_all(
    const float* __restrict__ Xk, const float* __restrict__ Xq,
    const float* __restrict__ Wk, const float* __restrict__ Wq,
    const int* __restrict__ adj,
    unsigned short* __restrict__ Yk, unsigned short* __restrict__ Yq,
    unsigned* __restrict__ mask) {
  __shared__ unsigned short wtl[256 * 64];   // 32 KB
  int bid = blockIdx.x;
  int tid = threadIdx.x;

  if (bid >= 512) {
    // ---- adjacency pack: wave handles one (b,q) row of 2048 ints ----
    int gwave = ((bid - 512) * 256 + tid) >> 6;
    int lane = tid & 63;
    const i32x4* p4 = (const i32x4*)(adj + (size_t)gwave * 2048) + lane;
    i32x4 av[8];
#pragma unroll
    for (int c = 0; c < 8; ++c)
      av[c] = __builtin_nontemporal_load(p4 + c * 64);
    unsigned* mrow = mask + (size_t)gwave * 64;
#pragma unroll
    for (int c = 0; c < 8; ++c) {
      i32x4 v = av[c];
      unsigned nib = (v[0] != 0 ? 1u : 0u) | (v[1] != 0 ? 2u : 0u) |
                     (v[2] != 0 ? 4u : 0u) | (v[3] != 0 ? 8u : 0u);
      unsigned m = nib << ((lane & 7) * 4);
      m |= __shfl_xor(m, 1);
      m |= __shfl_xor(m, 2);
      m |= __shfl_xor(m, 4);   // 8-lane group g=lane>>3 holds word c*8+g
      if ((lane & 7) == 0) mrow[c * 8 + (lane >> 3)] = m;
    }
    return;
  }

  // ---- projection ----
  const float* X;
  const float* W;
  unsigned short* Y;
  float scale;
  if (bid < 256) { X = Xk; W = Wk; Y = Yk; scale = 1.0f; }
  else           { X = Xq; W = Wq; Y = Yq; scale = 0.0625f; }
  int xb = bid & 255;
  int wave = tid >> 6, lane = tid & 63;
  int l31 = lane & 31, kh = lane >> 5;
  int r0 = xb * 128 + wave * 32;

  const float* xp = X + (size_t)(r0 + l31) * 256 + kh * 8;

  f32x16 acc[8];
#pragma unroll
  for (int ct = 0; ct < 8; ++ct)
#pragma unroll
    for (int i = 0; i < 16; ++i) acc[ct][i] = 0.0f;

#pragma unroll 1
  for (int s = 0; s < 4; ++s) {
    __syncthreads();   // previous stage fully consumed
    // stage W rows k = s*64 .. s*64+63 as bf16 W^T into LDS (swizzled)
#pragma unroll 16
    for (int kl = 0; kl < 64; ++kl) {
      int k = s * 64 + kl;
      float w = W[(size_t)k * 256 + tid] * scale;   // coalesced 1 KB/iter
      wtl[tid * 64 + (((kl >> 3) ^ (tid & 7)) << 3) + (kl & 7)] = f2bf(w);
    }
    __syncthreads();   // stage visible to all waves

#pragma unroll
    for (int kq = 0; kq < 4; ++kq) {
      int kk = s * 4 + kq;   // global 16-k index
      f32x4 a0 = *(const f32x4*)(xp + kk * 16);
      f32x4 a1 = *(const f32x4*)(xp + kk * 16 + 4);
      s16x8 af;
#pragma unroll
      for (int j = 0; j < 4; ++j) {
        af[j]     = (short)f2bf(a0[j]);
        af[4 + j] = (short)f2bf(a1[j]);
      }
      int bk = kq * 2 + kh;   // 16B-block index within stage, 0..7
#pragma unroll
      for (int ct = 0; ct < 8; ++ct) {
        int n = ct * 32 + l31;
        s16x8 bw = *(const s16x8*)(wtl + n * 64 + ((bk ^ (n & 7)) << 3));
        acc[ct] = mfma32(af, bw, acc[ct]);
      }
    }
  }

  // epilogue: scatter into 16-row-tile fragment order
  int kg2 = l31 >> 3, j = l31 & 7;
#pragma unroll
  for (int ct = 0; ct < 8; ++ct) {
#pragma unroll
    for (int r = 0; r < 16; ++r) {
      int rrow = (r & 3) + 8 * (r >> 2) + 4 * kh;
      int row = r0 + rrow;
      Y[((size_t)((row >> 4) * 8 + ct) * 64 + kg2 * 16 + (row & 15)) * 8 + j] =
          f2bf(acc[ct][r]);
    }
  }
}

// Fused scores + tanh-clip + mask + softmax. R22 structure with ONE change:
// P STASH IN REGISTERS (64 VGPR, static indices) instead of 128 KB LDS.
// Rationale: this kernel is LDS-capped to 1 block/CU regardless, so each
// wave may own up to 256 regs — the occupancy penalty that killed earlier
// register stashes (R11/R12 fought for a <=128 budget) cannot occur here.
// Removes 64 ds_write_b64 + 64 ds_read_b64 per wave from the critical path.
// Est. regs: aqA/B 64 + bkX/Y 64 + stash 64 + misc ~30 ~= 222 <= 256.
// Grid: (64, 16) = 1024 blocks, 512 threads (8 waves); wave w owns cols
// [w*256, w*256+256) as 16 col-tiles of 16. K ping-pong prefetch.
// XCD remap: xcd = lin&7 owns batches {2*xcd, 2*xcd+1} (2 MB K / L2).
__global__ __launch_bounds__(512, 1) void attn_kernel(
    const unsigned short* __restrict__ Kf, const unsigned short* __restrict__ Qf,
    const unsigned* __restrict__ mask, float* __restrict__ out) {
  int lin = blockIdx.y * 64 + blockIdx.x;
  int b  = (lin & 7) * 2 + ((lin >> 3) & 1);
  int qt = lin >> 4;                 // 0..63: 32-row tile within batch
  int q0 = qt * 32;
  int tid = threadIdx.x;
  int wave = tid >> 6, lane = tid & 63;
  int l15 = lane & 15, kg = lane >> 4;
  int colbase = wave * 256;

  __shared__ unsigned lmask[32 * 68];      // 8.7 KB: [row][word], stride 68
  __shared__ float wsum[8][32];
  __shared__ float rrecip[32];

  // ---- stage mask words: rows q0..q0+31, 64 words each (2048 words) ----
  {
    const i32x4* msrc = (const i32x4*)(mask + ((size_t)b * NQ + q0) * 64);
    i32x4 v = msrc[tid];
    int row = tid >> 4, w4 = tid & 15;          // word group w4*4..w4*4+3
    *(i32x4*)(lmask + row * 68 + w4 * 4) = v;   // 68%4==0: aligned
  }

  // Q fragments for subtiles A (rows q0..q0+15) and B (rows q0+16..q0+31)
  const unsigned short* qpA = Qf + (size_t)(b * 128 + 2 * qt) * 4096;
  s16x8 aqA[8], aqB[8];
#pragma unroll
  for (int kk = 0; kk < 8; ++kk) {
    aqA[kk] = __builtin_nontemporal_load(
        (const s16x8*)(qpA + ((size_t)kk * 64 + lane) * 8));
    aqB[kk] = __builtin_nontemporal_load(
        (const s16x8*)(qpA + 4096 + ((size_t)kk * 64 + lane) * 8));
  }

  __syncthreads();  // lmask staged cross-wave

  const unsigned short* kfb = Kf + (size_t)b * 128 * 4096;

  float rsumA[4] = {0.0f, 0.0f, 0.0f, 0.0f};
  float rsumB[4] = {0.0f, 0.0f, 0.0f, 0.0f};
  s16x8 bkX[8], bkY[8];
  unsigned pAl[16], pAh[16], pBl[16], pBh[16];   // P stash, static indices only

#define KLOAD(CT, DST)                                                         \
  {                                                                            \
    const unsigned short* kpt = kfb + (size_t)(wave * 16 + (CT)) * 4096;       \
    _Pragma("unroll") for (int kk = 0; kk < 8; ++kk)                           \
        DST[kk] = *(const s16x8*)(kpt + ((size_t)kk * 64 + lane) * 8);         \
  }

#define PROCESS(CT, BK)                                                        \
  {                                                                            \
    f32x4 accA = {0.0f, 0.0f, 0.0f, 0.0f};                                     \
    f32x4 accB = {0.0f, 0.0f, 0.0f, 0.0f};                                     \
    _Pragma("unroll") for (int kk = 0; kk < 8; ++kk) {                         \
      accA = mfma16(aqA[kk], BK[kk], accA);                                    \
      accB = mfma16(aqB[kk], BK[kk], accB);                                    \
    }                                                                          \
    unsigned shift = (unsigned)(((CT) & 1) * 16 + l15);                        \
    int wrd = wave * 8 + ((CT) >> 1);                                          \
    float pA[4], pB[4];                                                        \
    _Pragma("unroll") for (int r = 0; r < 4; ++r) {                            \
      unsigned mwA = lmask[(kg * 4 + r) * 68 + wrd];                           \
      unsigned mwB = lmask[(16 + kg * 4 + r) * 68 + wrd];                      \
      float eA = score_p(accA[r]);                                             \
      float eB = score_p(accB[r]);                                             \
      pA[r] = ((mwA >> shift) & 1u) ? eA : 0.0f;                               \
      pB[r] = ((mwB >> shift) & 1u) ? eB : 0.0f;                               \
      rsumA[r] += pA[r];                                                       \
      rsumB[r] += pB[r];                                                       \
    }                                                                          \
    pAl[CT] = (unsigned)f2bf(pA[0]) | ((unsigned)f2bf(pA[1]) << 16);           \
    pAh[CT] = (unsigned)f2bf(pA[2]) | ((unsigned)f2bf(pA[3]) << 16);           \
    pBl[CT] = (unsigned)f2bf(pB[0]) | ((unsigned)f2bf(pB[1]) << 16);           \
    pBh[CT] = (unsigned)f2bf(pB[2]) | ((unsigned)f2bf(pB[3]) << 16);           \
  }

  KLOAD(0, bkX)
#pragma unroll
  for (int cp = 0; cp < 8; ++cp) {
    KLOAD(2 * cp + 1, bkY)      // prefetch odd tile before consuming even
    PROCESS(2 * cp, bkX)
    if (cp < 7) KLOAD(2 * cp + 2, bkX)   // prefetch next even before odd
    PROCESS(2 * cp + 1, bkY)
  }
#undef KLOAD
#undef PROCESS

  // col-reduce within each 16-lane quarter (rows disjoint across quarters)
#pragma unroll
  for (int r = 0; r < 4; ++r) {
    float vA = rsumA[r], vB = rsumB[r];
    vA += __shfl_xor(vA, 1);  vB += __shfl_xor(vB, 1);
    vA += __shfl_xor(vA, 2);  vB += __shfl_xor(vB, 2);
    vA += __shfl_xor(vA, 4);  vB += __shfl_xor(vB, 4);
    vA += __shfl_xor(vA, 8);  vB += __shfl_xor(vB, 8);
    rsumA[r] = vA;  rsumB[r] = vB;
  }
  if (l15 == 0) {
#pragma unroll
    for (int r = 0; r < 4; ++r) {
      wsum[wave][kg * 4 + r]      = rsumA[r];
      wsum[wave][16 + kg * 4 + r] = rsumB[r];
    }
  }
  __syncthreads();
  if (tid < 32) {
    float s = 0.0f;
#pragma unroll
    for (int w = 0; w < 8; ++w) s += wsum[w][tid];
    rrecip[tid] = 1.0f / s;
  }
  __syncthreads();

  float rcA[4], rcB[4];
#pragma unroll
  for (int r = 0; r < 4; ++r) {
    rcA[r] = rrecip[kg * 4 + r];
    rcB[r] = rrecip[16 + kg * 4 + r];
  }

  // normalize from register stash, PLAIN stores (L2 write-combining)
  float* opA = out + ((size_t)b * NQ + q0 + kg * 4) * (size_t)NK + colbase + l15;
  float* opB = opA + (size_t)16 * NK;
#pragma unroll
  for (int ct = 0; ct < 16; ++ct) {
    float a0 = __builtin_bit_cast(float, pAl[ct] << 16);
    float a1 = __builtin_bit_cast(float, pAl[ct] & 0xffff0000u);
    float a2 = __builtin_bit_cast(float, pAh[ct] << 16);
    float a3 = __builtin_bit_cast(float, pAh[ct] & 0xffff0000u);
    opA[(size_t)0 * NK + ct * 16] = a0 * rcA[0];
    opA[(size_t)1 * NK + ct * 16] = a1 * rcA[1];
    opA[(size_t)2 * NK + ct * 16] = a2 * rcA[2];
    opA[(size_t)3 * NK + ct * 16] = a3 * rcA[3];
    float b0 = __builtin_bit_cast(float, pBl[ct] << 16);
    float b1 = __builtin_bit_cast(float, pBl[ct] & 0xffff0000u);
    float b2 = __builtin_bit_cast(float, pBh[ct] << 16);
    float b3 = __builtin_bit_cast(float, pBh[ct] & 0xffff0000u);
    opB[(size_t)0 * NK + ct * 16] = b0 * rcB[0];
    opB[(size_t)1 * NK + ct * 16] = b1 * rcB[1];
    opB[(size_t)2 * NK + ct * 16] = b2 * rcB[2];
    opB[(size_t)3 * NK + ct * 16] = b3 * rcB[3];
  }
}

extern "C" void kernel_launch(void* const* d_in, const int* in_sizes, int n_in,
                              void* d_out, int out_size, void* d_ws, size_t ws_size,
                              hipStream_t stream) {
  const float* k_in = (const float*)d_in[0];
  const float* q_in = (const float*)d_in[1];
  const int* adj    = (const int*)d_in[2];
  const float* Wk   = (const float*)d_in[3];
  const float* Wq   = (const float*)d_in[4];
  float* out = (float*)d_out;

  char* ws = (char*)d_ws;
  unsigned short* Kf  = (unsigned short*)(ws + (1u << 18));              // 16 MB
  unsigned short* Qf  = (unsigned short*)(ws + (1u << 18) + (1u << 24)); // 16 MB
  unsigned* maskbuf   = (unsigned*)(ws + (1u << 18) + (2u << 24));       // 8.4 MB

  prep_all<<<512 + 8192, 256, 0, stream>>>(k_in, q_in, Wk, Wq, adj,
                                           Kf, Qf, maskbuf);

  attn_kernel<<<dim3(64, 16), 512, 0, stream>>>(Kf, Qf, maskbuf, out);
}

// Round 25
// 206.417 us; speedup vs baseline: 1.4155x; 1.4155x over previous
//
#include <hip/hip_runtime.h>

#define BATCH 16
#define NQ 2048
#define NK 2048

typedef short s16x8 __attribute__((ext_vector_type(8)));
typedef __bf16 bf16x8 __attribute__((ext_vector_type(8)));
typedef float f32x16 __attribute__((ext_vector_type(16)));
typedef float f32x4 __attribute__((ext_vector_type(4)));
typedef int i32x4 __attribute__((ext_vector_type(4)));
typedef unsigned u32x2 __attribute__((ext_vector_type(2)));

static __device__ __forceinline__ unsigned short f2bf(float f) {
  unsigned u = __builtin_bit_cast(unsigned, f);
  u += 0x7FFFu + ((u >> 16) & 1u);   // round-to-nearest-even
  return (unsigned short)(u >> 16);
}

static __device__ __forceinline__ f32x16 mfma32(s16x8 a, s16x8 b, f32x16 c) {
  return __builtin_amdgcn_mfma_f32_32x32x16_bf16(
      __builtin_bit_cast(bf16x8, a), __builtin_bit_cast(bf16x8, b), c, 0, 0, 0);
}

static __device__ __forceinline__ f32x4 mfma16(s16x8 a, s16x8 b, f32x4 c) {
  return __builtin_amdgcn_mfma_f32_16x16x32_bf16(
      __builtin_bit_cast(bf16x8, a), __builtin_bit_cast(bf16x8, b), c, 0, 0, 0);
}

// p = exp(10*tanh(s) - 10) = exp2(-28.8539.../(e^(2s)+1)), e^(2s)=exp2(2.88539*s)
static __device__ __forceinline__ float score_p(float s) {
  float u = __builtin_amdgcn_exp2f(s * 2.885390081777927f);
  return __builtin_amdgcn_exp2f(-28.853900817779268f * __builtin_amdgcn_rcpf(u + 1.0f));
}

// MERGED prep kernel (at HBM roofline ~56 us): pack_adj + projections.
//  - blocks 0..255:   K projection (blocks stage their own W^T in LDS)
//  - blocks 256..511: Q projection (scale 1/16 folded)
//  - blocks 512..8703: adjacency bit-pack (NT i32x4 + nibble/shfl-OR)
__global__ __launch_bounds__(256, 2) void prep_all(
    const float* __restrict__ Xk, const float* __restrict__ Xq,
    const float* __restrict__ Wk, const float* __restrict__ Wq,
    const int* __restrict__ adj,
    unsigned short* __restrict__ Yk, unsigned short* __restrict__ Yq,
    unsigned* __restrict__ mask) {
  __shared__ unsigned short wtl[256 * 64];   // 32 KB
  int bid = blockIdx.x;
  int tid = threadIdx.x;

  if (bid >= 512) {
    // ---- adjacency pack: wave handles one (b,q) row of 2048 ints ----
    int gwave = ((bid - 512) * 256 + tid) >> 6;
    int lane = tid & 63;
    const i32x4* p4 = (const i32x4*)(adj + (size_t)gwave * 2048) + lane;
    i32x4 av[8];
#pragma unroll
    for (int c = 0; c < 8; ++c)
      av[c] = __builtin_nontemporal_load(p4 + c * 64);
    unsigned* mrow = mask + (size_t)gwave * 64;
#pragma unroll
    for (int c = 0; c < 8; ++c) {
      i32x4 v = av[c];
      unsigned nib = (v[0] != 0 ? 1u : 0u) | (v[1] != 0 ? 2u : 0u) |
                     (v[2] != 0 ? 4u : 0u) | (v[3] != 0 ? 8u : 0u);
      unsigned m = nib << ((lane & 7) * 4);
      m |= __shfl_xor(m, 1);
      m |= __shfl_xor(m, 2);
      m |= __shfl_xor(m, 4);   // 8-lane group g=lane>>3 holds word c*8+g
      if ((lane & 7) == 0) mrow[c * 8 + (lane >> 3)] = m;
    }
    return;
  }

  // ---- projection ----
  const float* X;
  const float* W;
  unsigned short* Y;
  float scale;
  if (bid < 256) { X = Xk; W = Wk; Y = Yk; scale = 1.0f; }
  else           { X = Xq; W = Wq; Y = Yq; scale = 0.0625f; }
  int xb = bid & 255;
  int wave = tid >> 6, lane = tid & 63;
  int l31 = lane & 31, kh = lane >> 5;
  int r0 = xb * 128 + wave * 32;

  const float* xp = X + (size_t)(r0 + l31) * 256 + kh * 8;

  f32x16 acc[8];
#pragma unroll
  for (int ct = 0; ct < 8; ++ct)
#pragma unroll
    for (int i = 0; i < 16; ++i) acc[ct][i] = 0.0f;

#pragma unroll 1
  for (int s = 0; s < 4; ++s) {
    __syncthreads();   // previous stage fully consumed
    // stage W rows k = s*64 .. s*64+63 as bf16 W^T into LDS (swizzled)
#pragma unroll 16
    for (int kl = 0; kl < 64; ++kl) {
      int k = s * 64 + kl;
      float w = W[(size_t)k * 256 + tid] * scale;   // coalesced 1 KB/iter
      wtl[tid * 64 + (((kl >> 3) ^ (tid & 7)) << 3) + (kl & 7)] = f2bf(w);
    }
    __syncthreads();   // stage visible to all waves

#pragma unroll
    for (int kq = 0; kq < 4; ++kq) {
      int kk = s * 4 + kq;   // global 16-k index
      f32x4 a0 = *(const f32x4*)(xp + kk * 16);
      f32x4 a1 = *(const f32x4*)(xp + kk * 16 + 4);
      s16x8 af;
#pragma unroll
      for (int j = 0; j < 4; ++j) {
        af[j]     = (short)f2bf(a0[j]);
        af[4 + j] = (short)f2bf(a1[j]);
      }
      int bk = kq * 2 + kh;   // 16B-block index within stage, 0..7
#pragma unroll
      for (int ct = 0; ct < 8; ++ct) {
        int n = ct * 32 + l31;
        s16x8 bw = *(const s16x8*)(wtl + n * 64 + ((bk ^ (n & 7)) << 3));
        acc[ct] = mfma32(af, bw, acc[ct]);
      }
    }
  }

  // epilogue: scatter into 16-row-tile fragment order
  int kg2 = l31 >> 3, j = l31 & 7;
#pragma unroll
  for (int ct = 0; ct < 8; ++ct) {
#pragma unroll
    for (int r = 0; r < 16; ++r) {
      int rrow = (r & 3) + 8 * (r >> 2) + 4 * kh;
      int row = r0 + rrow;
      Y[((size_t)((row >> 4) * 8 + ct) * 64 + kg2 * 16 + (row & 15)) * 8 + j] =
          f2bf(acc[ct][r]);
    }
  }
}

// Fused scores + tanh-clip + mask + softmax (R22 EXACT — best known attn:
// probed from 8 directions, every change regressed). 32 Q-rows per block,
// A/B subtiles share every K fragment; K ping-pong prefetch; P stash in
// LDS 128 KB; masks staged 8 KB -> LDS; plain output stores.
// Grid: (64, 16) = 1024 blocks, 512 threads (8 waves).
// XCD remap: xcd = lin&7 owns batches {2*xcd, 2*xcd+1} (2 MB K / L2).
__global__ __launch_bounds__(512, 1) void attn_kernel(
    const unsigned short* __restrict__ Kf, const unsigned short* __restrict__ Qf,
    const unsigned* __restrict__ mask, float* __restrict__ out) {
  int lin = blockIdx.y * 64 + blockIdx.x;
  int b  = (lin & 7) * 2 + ((lin >> 3) & 1);
  int qt = lin >> 4;                 // 0..63: 32-row tile within batch
  int q0 = qt * 32;
  int tid = threadIdx.x;
  int wave = tid >> 6, lane = tid & 63;
  int l15 = lane & 15, kg = lane >> 4;
  int colbase = wave * 256;

  __shared__ unsigned plds[8 * 16 * 256];  // 128 KB: [wave][ct][A:128|B:128]
  __shared__ unsigned lmask[32 * 68];      // 8.7 KB: [row][word], stride 68
  __shared__ float wsum[8][32];
  __shared__ float rrecip[32];

  // ---- stage mask words: rows q0..q0+31, 64 words each (2048 words) ----
  {
    const i32x4* msrc = (const i32x4*)(mask + ((size_t)b * NQ + q0) * 64);
    i32x4 v = msrc[tid];
    int row = tid >> 4, w4 = tid & 15;          // word group w4*4..w4*4+3
    *(i32x4*)(lmask + row * 68 + w4 * 4) = v;   // 68%4==0: aligned
  }

  // Q fragments for subtiles A (rows q0..q0+15) and B (rows q0+16..q0+31)
  const unsigned short* qpA = Qf + (size_t)(b * 128 + 2 * qt) * 4096;
  s16x8 aqA[8], aqB[8];
#pragma unroll
  for (int kk = 0; kk < 8; ++kk) {
    aqA[kk] = __builtin_nontemporal_load(
        (const s16x8*)(qpA + ((size_t)kk * 64 + lane) * 8));
    aqB[kk] = __builtin_nontemporal_load(
        (const s16x8*)(qpA + 4096 + ((size_t)kk * 64 + lane) * 8));
  }

  __syncthreads();  // lmask staged cross-wave

  const unsigned short* kfb = Kf + (size_t)b * 128 * 4096;
  unsigned* pl = plds + wave * 4096 + lane * 2;

  float rsumA[4] = {0.0f, 0.0f, 0.0f, 0.0f};
  float rsumB[4] = {0.0f, 0.0f, 0.0f, 0.0f};
  s16x8 bkX[8], bkY[8];

#define KLOAD(CT, DST)                                                         \
  {                                                                            \
    const unsigned short* kpt = kfb + (size_t)(wave * 16 + (CT)) * 4096;       \
    _Pragma("unroll") for (int kk = 0; kk < 8; ++kk)                           \
        DST[kk] = *(const s16x8*)(kpt + ((size_t)kk * 64 + lane) * 8);         \
  }

#define PROCESS(CT, BK)                                                        \
  {                                                                            \
    f32x4 accA = {0.0f, 0.0f, 0.0f, 0.0f};                                     \
    f32x4 accB = {0.0f, 0.0f, 0.0f, 0.0f};                                     \
    _Pragma("unroll") for (int kk = 0; kk < 8; ++kk) {                         \
      accA = mfma16(aqA[kk], BK[kk], accA);                                    \
      accB = mfma16(aqB[kk], BK[kk], accB);                                    \
    }                                                                          \
    unsigned shift = (unsigned)(((CT) & 1) * 16 + l15);                        \
    int wrd = wave * 8 + ((CT) >> 1);                                          \
    float pA[4], pB[4];                                                        \
    _Pragma("unroll") for (int r = 0; r < 4; ++r) {                            \
      unsigned mwA = lmask[(kg * 4 + r) * 68 + wrd];                           \
      unsigned mwB = lmask[(16 + kg * 4 + r) * 68 + wrd];                      \
      float eA = score_p(accA[r]);                                             \
      float eB = score_p(accB[r]);                                             \
      pA[r] = ((mwA >> shift) & 1u) ? eA : 0.0f;                               \
      pB[r] = ((mwB >> shift) & 1u) ? eB : 0.0f;                               \
      rsumA[r] += pA[r];                                                       \
      rsumB[r] += pB[r];                                                       \
    }                                                                          \
    u32x2 vA, vB;                                                              \
    vA[0] = (unsigned)f2bf(pA[0]) | ((unsigned)f2bf(pA[1]) << 16);             \
    vA[1] = (unsigned)f2bf(pA[2]) | ((unsigned)f2bf(pA[3]) << 16);             \
    vB[0] = (unsigned)f2bf(pB[0]) | ((unsigned)f2bf(pB[1]) << 16);             \
    vB[1] = (unsigned)f2bf(pB[2]) | ((unsigned)f2bf(pB[3]) << 16);             \
    *(u32x2*)(pl + (CT)*256) = vA;                                             \
    *(u32x2*)(pl + (CT)*256 + 128) = vB;                                       \
  }

  KLOAD(0, bkX)
#pragma unroll
  for (int cp = 0; cp < 8; ++cp) {
    KLOAD(2 * cp + 1, bkY)      // prefetch odd tile before consuming even
    PROCESS(2 * cp, bkX)
    if (cp < 7) KLOAD(2 * cp + 2, bkX)   // prefetch next even before odd
    PROCESS(2 * cp + 1, bkY)
  }
#undef KLOAD
#undef PROCESS

  // col-reduce within each 16-lane quarter (rows disjoint across quarters)
#pragma unroll
  for (int r = 0; r < 4; ++r) {
    float vA = rsumA[r], vB = rsumB[r];
    vA += __shfl_xor(vA, 1);  vB += __shfl_xor(vB, 1);
    vA += __shfl_xor(vA, 2);  vB += __shfl_xor(vB, 2);
    vA += __shfl_xor(vA, 4);  vB += __shfl_xor(vB, 4);
    vA += __shfl_xor(vA, 8);  vB += __shfl_xor(vB, 8);
    rsumA[r] = vA;  rsumB[r] = vB;
  }
  if (l15 == 0) {
#pragma unroll
    for (int r = 0; r < 4; ++r) {
      wsum[wave][kg * 4 + r]      = rsumA[r];
      wsum[wave][16 + kg * 4 + r] = rsumB[r];
    }
  }
  __syncthreads();
  if (tid < 32) {
    float s = 0.0f;
#pragma unroll
    for (int w = 0; w < 8; ++w) s += wsum[w][tid];
    rrecip[tid] = 1.0f / s;
  }
  __syncthreads();

  float rcA[4], rcB[4];
#pragma unroll
  for (int r = 0; r < 4; ++r) {
    rcA[r] = rrecip[kg * 4 + r];
    rcB[r] = rrecip[16 + kg * 4 + r];
  }

  // read P back from LDS, normalize, PLAIN stores (L2 write-combining)
  float* opA = out + ((size_t)b * NQ + q0 + kg * 4) * (size_t)NK + colbase + l15;
  float* opB = opA + (size_t)16 * NK;
#pragma unroll 4
  for (int ct = 0; ct < 16; ++ct) {
    u32x2 vA = *(const u32x2*)(pl + ct * 256);
    u32x2 vB = *(const u32x2*)(pl + ct * 256 + 128);
#pragma unroll
    for (int r = 0; r < 4; ++r) {
      unsigned w = (r < 2) ? vA[0] : vA[1];
      float p = __builtin_bit_cast(float, (r & 1) ? (w & 0xffff0000u) : (w << 16));
      opA[(size_t)r * NK + ct * 16] = p * rcA[r];
    }
#pragma unroll
    for (int r = 0; r < 4; ++r) {
      unsigned w = (r < 2) ? vB[0] : vB[1];
      float p = __builtin_bit_cast(float, (r & 1) ? (w & 0xffff0000u) : (w << 16));
      opB[(size_t)r * NK + ct * 16] = p * rcB[r];
    }
  }
}

extern "C" void kernel_launch(void* const* d_in, const int* in_sizes, int n_in,
                              void* d_out, int out_size, void* d_ws, size_t ws_size,
                              hipStream_t stream) {
  const float* k_in = (const float*)d_in[0];
  const float* q_in = (const float*)d_in[1];
  const int* adj    = (const int*)d_in[2];
  const float* Wk   = (const float*)d_in[3];
  const float* Wq   = (const float*)d_in[4];
  float* out = (float*)d_out;

  char* ws = (char*)d_ws;
  unsigned short* Kf  = (unsigned short*)(ws + (1u << 18));              // 16 MB
  unsigned short* Qf  = (unsigned short*)(ws + (1u << 18) + (1u << 24)); // 16 MB
  unsigned* maskbuf   = (unsigned*)(ws + (1u << 18) + (2u << 24));       // 8.4 MB

  prep_all<<<512 + 8192, 256, 0, stream>>>(k_in, q_in, Wk, Wq, adj,
                                           Kf, Qf, maskbuf);

  attn_kernel<<<dim3(64, 16), 512, 0, stream>>>(Kf, Qf, maskbuf, out);
}